// Round 15
// baseline (1158.882 us; speedup 1.0000x reference)
//
#include <hip/hip_runtime.h>
#include <hip/hip_bf16.h>
#include <hip/hip_fp16.h>
#include <limits.h>
#include <math.h>

#define F_IN 92
#define H 35
#define HP 36        // fp32 row stride (h): 144 B = 9 x float4
#define HP2 36       // fp16 row stride (xl, e_out): 72 B = 9 x 8B
#define HOUT 64
#define NL 3
#define NEG_SLOPE 0.2f
#define NSLICE 8
#define SCH 2048     // scan chunk per block (256 thr x 8)

typedef int iv4 __attribute__((ext_vector_type(4)));

// ------------------------------------------------------------------
// folded attention vectors: w1[l] = W_l @ a_n, w2[l] = W_l @ a_e
// ------------------------------------------------------------------
__global__ void wfold_all_kernel(const float* __restrict__ lin_W, const float* __restrict__ att,
                                 float* __restrict__ w1, float* __restrict__ w2) {
    int k = threadIdx.x;
    if (k < H) {
        for (int l = 0; l < NL; ++l) {
            const float* W  = lin_W + (size_t)l * H * H;
            const float* an = att + (size_t)l * 2 * H;
            const float* ae = an + H;
            float a1 = 0.f, a2 = 0.f;
#pragma unroll
            for (int j = 0; j < H; ++j) {
                float wkj = W[k * H + j];
                a1 += wkj * an[j];
                a2 += wkj * ae[j];
            }
            w1[l * H + k] = a1;
            w2[l * H + k] = a2;
        }
    }
}

// he_s[r] = dot(he[r,:], vec)  (he is UNPADDED stride H from input)
__global__ void rowdot_he_kernel(const float* __restrict__ in, const float* __restrict__ vec,
                                 float* __restrict__ s, int R, int stride_out) {
    __shared__ float sA[H];
    for (int t = threadIdx.x; t < H; t += blockDim.x) sA[t] = vec[t];
    __syncthreads();
    int stride = gridDim.x * blockDim.x;
    for (int r = blockIdx.x * blockDim.x + threadIdx.x; r < R; r += stride) {
        const float* xr = in + (long)r * H;
        float acc = 0.f;
#pragma unroll
        for (int k = 0; k < H; ++k) acc += xr[k] * sA[k];
        s[(long)r * stride_out] = acc;
    }
}

// ------------------------------------------------------------------
// embed fused: wave-per-row; produces h (fp32), xl_h (fp16, layer 0),
// s_n (layer 0). Row staged through wave-local LDS (same-wave pattern).
// ------------------------------------------------------------------
__global__ void embed_fused_kernel(const float* __restrict__ x, const float* __restrict__ eW,
                                   const float* __restrict__ eb, const float* __restrict__ W0,
                                   const float* __restrict__ w1_0,
                                   float* __restrict__ h, __half* __restrict__ xl_h,
                                   float* __restrict__ s_n, int N) {
    __shared__ float sEW[F_IN * H];
    __shared__ float sW[H * H];
    __shared__ float sw1[H];
    __shared__ float sb[H];
    __shared__ float shrow[4][HP];
    __shared__ __half shh[4][HP];
    for (int t = threadIdx.x; t < F_IN * H; t += blockDim.x) sEW[t] = eW[t];
    for (int t = threadIdx.x; t < H * H; t += blockDim.x) sW[t] = W0[t];
    if (threadIdx.x < H) { sw1[threadIdx.x] = w1_0[threadIdx.x]; sb[threadIdx.x] = eb[threadIdx.x]; }
    __syncthreads();
    int lane = threadIdx.x & 63, ws = threadIdx.x >> 6;
    int wid = (blockIdx.x * blockDim.x + threadIdx.x) >> 6;
    int nw = (gridDim.x * blockDim.x) >> 6;
    for (int n = wid; n < N; n += nw) {
        const float* xr = x + (long)n * F_IN;
        if (lane < H) {
            float acc = sb[lane];
#pragma unroll 4
            for (int k = 0; k < F_IN; ++k) acc += xr[k] * sEW[k * H + lane];
            shrow[ws][lane] = acc;
        } else if (lane == H) {
            shrow[ws][H] = 0.f;
        }
        // h row write (wave-local LDS dependency: compiler inserts lgkmcnt wait)
        if (lane < 9) ((float4*)(h + (size_t)n * HP))[lane] = ((const float4*)&shrow[ws][0])[lane];
        // produce xl_h and s_n for layer 0
        if (lane < H) {
            float a = 0.f;
#pragma unroll
            for (int k = 0; k < H; ++k) a += shrow[ws][k] * sW[k * H + lane];
            shh[ws][lane] = __float2half(a);
        } else if (lane == H) {
            float a2 = 0.f;
#pragma unroll
            for (int k = 0; k < H; ++k) a2 += shrow[ws][k] * sw1[k];
            s_n[n] = a2;
            shh[ws][H] = __float2half(0.f);
        }
        if (lane < 9) ((uint2*)(xl_h + (size_t)n * HP2))[lane] = ((const uint2*)&shh[ws][0])[lane];
    }
}

// ------------------------------------------------------------------
// CSR build — sliced scatter (r8) + hierarchical scan (r9), validated
// ------------------------------------------------------------------

__global__ void count_sliced_kernel(const int* __restrict__ ni, const int* __restrict__ ei,
                                    int* __restrict__ ncnt, int* __restrict__ ecnt,
                                    int ninc, int wN, int wE) {
    int s = blockIdx.x & (NSLICE - 1);
    int loN = s * wN, hiN = loN + wN;
    int loE = s * wE, hiE = loE + wE;
    int nblk = gridDim.x >> 3;
    int bid = blockIdx.x >> 3;
    int nvec = ninc >> 2;
    int stride = nblk * blockDim.x;
    for (int q = bid * blockDim.x + threadIdx.x; q < nvec; q += stride) {
        iv4 v4 = __builtin_nontemporal_load((const iv4*)ni + q);
        iv4 e4 = __builtin_nontemporal_load((const iv4*)ei + q);
#pragma unroll
        for (int u = 0; u < 4; ++u) {
            int e = e4[u], v = v4[u];
            if (e >= loE && e < hiE) atomicAdd(&ecnt[e], 1);
            if (v >= loN && v < hiN) atomicAdd(&ncnt[v], 1);
        }
    }
    if (bid == 0) {
        for (int i = (nvec << 2) + threadIdx.x; i < ninc; i += blockDim.x) {
            int v = ni[i], e = ei[i];
            if (e >= loE && e < hiE) atomicAdd(&ecnt[e], 1);
            if (v >= loN && v < hiN) atomicAdd(&ncnt[v], 1);
        }
    }
}

__device__ __forceinline__ int wave_sum_i(int s) {
#pragma unroll
    for (int off = 32; off; off >>= 1) s += __shfl_xor(s, off);
    return s;
}

__global__ void bsum2_kernel(const int* __restrict__ cnt0, int nb0, int n0,
                             const int* __restrict__ cnt1, int n1,
                             int* __restrict__ bsums) {
    int b = blockIdx.x;
    const int* c; int n; int base;
    if (b < nb0) { c = cnt0; n = n0; base = b * SCH; }
    else         { c = cnt1; n = n1; base = (b - nb0) * SCH; }
    int t = threadIdx.x;
    int hi = base + SCH; if (hi > n) hi = n;
    int s = 0;
    for (int i = base + t; i < hi; i += 256) s += c[i];
    s = wave_sum_i(s);
    __shared__ int ws[4];
    if ((t & 63) == 0) ws[t >> 6] = s;
    __syncthreads();
    if (t == 0) bsums[b] = ws[0] + ws[1] + ws[2] + ws[3];
}

__global__ void scan_bsums_kernel(int* __restrict__ bsums, int nb0, int nb1) {
    int t = threadIdx.x;
    if (t == 0) {
        int acc = 0;
        for (int i = 0; i < nb0; ++i) { int v = bsums[i]; bsums[i] = acc; acc += v; }
    } else if (t == 1) {
        int acc = 0;
        for (int i = nb0; i < nb0 + nb1; ++i) { int v = bsums[i]; bsums[i] = acc; acc += v; }
    }
}

__global__ void scan_write2_kernel(const int* __restrict__ cnt0, int* __restrict__ ptr0,
                                   int* __restrict__ cur0, int nb0, int n0,
                                   const int* __restrict__ cnt1, int* __restrict__ ptr1,
                                   int* __restrict__ cur1, int n1,
                                   const int* __restrict__ bsums, int ninc) {
    int b = blockIdx.x;
    const int* c; int* p; int* u; int n; int base;
    if (b < nb0) { c = cnt0; p = ptr0; u = cur0; n = n0; base = b * SCH; }
    else         { c = cnt1; p = ptr1; u = cur1; n = n1; base = (b - nb0) * SCH; }
    int off = bsums[b];
    int t = threadIdx.x;
    int lo = base + t * 8;
    int vals[8];
    int s = 0;
#pragma unroll
    for (int k = 0; k < 8; ++k) {
        int i = lo + k;
        int v = (i < n) ? c[i] : 0;
        vals[k] = s;
        s += v;
    }
    __shared__ int lds[256];
    lds[t] = s;
    __syncthreads();
    for (int o2 = 1; o2 < 256; o2 <<= 1) {
        int v = (t >= o2) ? lds[t - o2] : 0;
        __syncthreads();
        lds[t] += v;
        __syncthreads();
    }
    int tbase = off + ((t == 0) ? 0 : lds[t - 1]);
#pragma unroll
    for (int k = 0; k < 8; ++k) {
        int i = lo + k;
        if (i < n) { int val = tbase + vals[k]; p[i] = val; u[i] = val; }
    }
    if (b == 0 && t == 0) { ptr0[n0] = ninc; ptr1[n1] = ninc; }
}

__global__ void csr_fill_sliced_kernel(const int* __restrict__ ni, const int* __restrict__ ei,
                                       int* __restrict__ ecur, int* __restrict__ ncur,
                                       int* __restrict__ enode, int* __restrict__ nedge,
                                       int ninc, int wN, int wE) {
    int s = blockIdx.x & (NSLICE - 1);
    int loN = s * wN, hiN = loN + wN;
    int loE = s * wE, hiE = loE + wE;
    int nblk = gridDim.x >> 3;
    int bid = blockIdx.x >> 3;
    int nvec = ninc >> 2;
    int stride = nblk * blockDim.x;
    for (int q = bid * blockDim.x + threadIdx.x; q < nvec; q += stride) {
        iv4 v4 = __builtin_nontemporal_load((const iv4*)ni + q);
        iv4 e4 = __builtin_nontemporal_load((const iv4*)ei + q);
#pragma unroll
        for (int u = 0; u < 4; ++u) {
            int e = e4[u], v = v4[u];
            if (e >= loE && e < hiE) {
                int p = atomicAdd(&ecur[e], 1);
                enode[p] = v;
            }
            if (v >= loN && v < hiN) {
                int p = atomicAdd(&ncur[v], 1);
                nedge[p] = e;
            }
        }
    }
    if (bid == 0) {
        for (int i = (nvec << 2) + threadIdx.x; i < ninc; i += blockDim.x) {
            int v = ni[i], e = ei[i];
            if (e >= loE && e < hiE) { int p = atomicAdd(&ecur[e], 1); enode[p] = v; }
            if (v >= loN && v < hiN) { int p = atomicAdd(&ncur[v], 1); nedge[p] = e; }
        }
    }
}

// ------------------------------------------------------------------
// fused sparse passes — 7 groups x 9 lanes; fp16 rows, fp32 accumulation
// ------------------------------------------------------------------

__device__ __forceinline__ float wave_max(float m) {
#pragma unroll
    for (int off = 32; off; off >>= 1) m = fmaxf(m, __shfl_xor(m, off));
    return m;
}
__device__ __forceinline__ float wave_sum(float s) {
#pragma unroll
    for (int off = 32; off; off >>= 1) s += __shfl_xor(s, off);
    return s;
}

__device__ __forceinline__ void grouped_gather_h(const __half* __restrict__ src,
                                                 const float* shA, const int* shV,
                                                 int cnt, int g, int l, float4& acc) {
    if (g < 7) {
        for (int k = g; k < cnt; k += 7) {
            float ak = shA[k];
            int vk = shV[k];
            uint2 raw = ((const uint2*)(src + (size_t)vk * HP2))[l];
            __half2 h01 = *reinterpret_cast<const __half2*>(&raw.x);
            __half2 h23 = *reinterpret_cast<const __half2*>(&raw.y);
            float2 f01 = __half22float2(h01);
            float2 f23 = __half22float2(h23);
            acc.x += ak * f01.x; acc.y += ak * f01.y;
            acc.z += ak * f23.x; acc.w += ak * f23.y;
        }
    }
}

__device__ __forceinline__ void group_reduce(float4& acc, int lane, int l) {
#pragma unroll
    for (int gg = 1; gg < 7; ++gg) {
        int src = l + 9 * gg;
        float ox = __shfl(acc.x, src);
        float oy = __shfl(acc.y, src);
        float oz = __shfl(acc.z, src);
        float ow = __shfl(acc.w, src);
        if (lane < 9) { acc.x += ox; acc.y += oy; acc.z += oz; acc.w += ow; }
    }
}

// per edge e: softmax + weighted accumulation into e_out_h[e,:] (fp16, stride HP2)
__global__ void edge_pass_kernel(const int* __restrict__ eptr, const int* __restrict__ enode,
                                 const float* __restrict__ s_n, float* __restrict__ epack,
                                 const __half* __restrict__ xl_h,
                                 __half* __restrict__ e_out_h, int E) {
    __shared__ float shA[4][64];
    __shared__ int   shV[4][64];
    int lane = threadIdx.x & 63;
    int ws = threadIdx.x >> 6;
    int g = lane / 9, l = lane - g * 9;
    int wid = (blockIdx.x * blockDim.x + threadIdx.x) >> 6;
    int nw = (gridDim.x * blockDim.x) >> 6;
    for (int e = wid; e < E; e += nw) {
        int lo = eptr[e], hi = eptr[e + 1];
        int deg = hi - lo;
        float se = epack[4 * (long)e];
        float binv = deg > 0 ? 1.f / (float)deg : 0.f;
        float4 acc = {0.f, 0.f, 0.f, 0.f};
        float mm, rec;
        if (deg <= 64) {
            int v = 0; float sc = -INFINITY;
            if (lane < deg) {
                v = enode[lo + lane];
                sc = s_n[v] + se;
                sc = sc >= 0.f ? sc : NEG_SLOPE * sc;
            }
            float m = wave_max(sc);
            mm = (m == -INFINITY) ? 0.f : m;
            float ex = (lane < deg) ? expf(sc - mm) : 0.f;
            float s = wave_sum(ex);
            rec = 1.f / (s + 1e-16f);
            shA[ws][lane] = ex * rec * binv;
            shV[ws][lane] = v;
            grouped_gather_h(xl_h, shA[ws], shV[ws], deg, g, l, acc);
        } else {
            float m = -INFINITY;
            for (int k = lo + lane; k < hi; k += 64) {
                float sc = s_n[enode[k]] + se;
                sc = sc >= 0.f ? sc : NEG_SLOPE * sc;
                m = fmaxf(m, sc);
            }
            m = wave_max(m);
            mm = (m == -INFINITY) ? 0.f : m;
            float s = 0.f;
            for (int k = lo + lane; k < hi; k += 64) {
                float sc = s_n[enode[k]] + se;
                sc = sc >= 0.f ? sc : NEG_SLOPE * sc;
                s += expf(sc - mm);
            }
            s = wave_sum(s);
            rec = 1.f / (s + 1e-16f);
            float cb = rec * binv;
            for (int base = lo; base < hi; base += 64) {
                int v = 0; float a = 0.f;
                if (base + lane < hi) {
                    v = enode[base + lane];
                    float sc = s_n[v] + se;
                    sc = sc >= 0.f ? sc : NEG_SLOPE * sc;
                    a = expf(sc - mm) * cb;
                }
                shA[ws][lane] = a;
                shV[ws][lane] = v;
                int cn = hi - base; if (cn > 64) cn = 64;
                grouped_gather_h(xl_h, shA[ws], shV[ws], cn, g, l, acc);
            }
        }
        group_reduce(acc, lane, l);
        if (lane < 9) {
            __half2 p0 = __floats2half2_rn(acc.x, acc.y);
            __half2 p1 = __floats2half2_rn(acc.z, acc.w);
            uint2 wv;
            wv.x = *reinterpret_cast<unsigned*>(&p0);
            wv.y = *reinterpret_cast<unsigned*>(&p1);
            ((uint2*)(e_out_h + (size_t)e * HP2))[lane] = wv;
        }
        if (lane == 0) { epack[4 * (long)e + 1] = mm; epack[4 * (long)e + 2] = rec; }
    }
}

// per node v: h[v,:] = Dinv * sum alpha_i * e_out_h[e_i,:] + bias  (h fp32)
// fused epilogue (produce=1): xl_h[v,:] = h[v,:] @ Wn  (fp16), s_n[v] = h[v,:] @ w1n
__global__ void node_pass_kernel(const int* __restrict__ nptr, const int* __restrict__ nedge,
                                 const float* __restrict__ s_n_in, const float* __restrict__ epack,
                                 const __half* __restrict__ e_out_h, const float* __restrict__ bias,
                                 const float* __restrict__ Wn, const float* __restrict__ w1n,
                                 int produce,
                                 float* __restrict__ hout, __half* __restrict__ xl_out,
                                 float* __restrict__ snout, int N) {
    __shared__ float shA[4][64];
    __shared__ int   shE[4][64];
    __shared__ float sb[HP];
    __shared__ float sW[H * H];
    __shared__ float sw1[H];
    __shared__ float shrow[4][HP];
    __shared__ __half shh[4][HP];
    if (threadIdx.x < HP) sb[threadIdx.x] = (threadIdx.x < H) ? bias[threadIdx.x] : 0.f;
    for (int t = threadIdx.x; t < H * H; t += blockDim.x) sW[t] = Wn[t];
    if (threadIdx.x < H) sw1[threadIdx.x] = w1n[threadIdx.x];
    __syncthreads();
    int lane = threadIdx.x & 63;
    int ws = threadIdx.x >> 6;
    int g = lane / 9, l = lane - g * 9;
    int wid = (blockIdx.x * blockDim.x + threadIdx.x) >> 6;
    int nw = (gridDim.x * blockDim.x) >> 6;
    for (int v = wid; v < N; v += nw) {
        int lo = nptr[v], hi = nptr[v + 1];
        int deg = hi - lo;
        float dinv = deg > 0 ? 1.f / (float)deg : 0.f;
        float sn = s_n_in[v];
        float4 acc = {0.f, 0.f, 0.f, 0.f};
        if (deg <= 64) {
            int e = 0; float a = 0.f;
            if (lane < deg) {
                e = nedge[lo + lane];
                float4 p = ((const float4*)epack)[e];
                float sc = sn + p.x;
                sc = sc >= 0.f ? sc : NEG_SLOPE * sc;
                a = expf(sc - p.y) * p.z;
            }
            shA[ws][lane] = a;
            shE[ws][lane] = e;
            grouped_gather_h(e_out_h, shA[ws], shE[ws], deg, g, l, acc);
        } else {
            for (int base = lo; base < hi; base += 64) {
                int e = 0; float a = 0.f;
                if (base + lane < hi) {
                    e = nedge[base + lane];
                    float4 p = ((const float4*)epack)[e];
                    float sc = sn + p.x;
                    sc = sc >= 0.f ? sc : NEG_SLOPE * sc;
                    a = expf(sc - p.y) * p.z;
                }
                shA[ws][lane] = a;
                shE[ws][lane] = e;
                int cn = hi - base; if (cn > 64) cn = 64;
                grouped_gather_h(e_out_h, shA[ws], shE[ws], cn, g, l, acc);
            }
        }
        group_reduce(acc, lane, l);
        if (lane < 9) {
            float4 bb = ((const float4*)sb)[lane];
            float4 r;
            r.x = dinv * acc.x + bb.x;
            r.y = dinv * acc.y + bb.y;
            r.z = dinv * acc.z + bb.z;
            r.w = dinv * acc.w + bb.w;
            ((float4*)(hout + (size_t)v * HP))[lane] = r;
            ((float4*)&shrow[ws][0])[lane] = r;    // stage row for fused lin (pad col = 0)
        }
        if (produce) {
            // wave-local LDS dep: lanes read the row lanes 0..8 just wrote
            if (lane < H) {
                float a = 0.f;
#pragma unroll
                for (int k = 0; k < H; ++k) a += shrow[ws][k] * sW[k * H + lane];
                shh[ws][lane] = __float2half(a);
            } else if (lane == H) {
                float a2 = 0.f;
#pragma unroll
                for (int k = 0; k < H; ++k) a2 += shrow[ws][k] * sw1[k];
                snout[v] = a2;
                shh[ws][H] = __float2half(0.f);
            }
            if (lane < 9) ((uint2*)(xl_out + (size_t)v * HP2))[lane] = ((const uint2*)&shh[ws][0])[lane];
        }
    }
}

// ------------------------------------------------------------------
// fused pooling (batch sorted -> binary search) + MLP head (h stride HP)
// ------------------------------------------------------------------
__global__ void pool_head_kernel(const float* __restrict__ h, const int* __restrict__ batch,
                                 int N, const float* __restrict__ pW, const float* __restrict__ pb,
                                 const float* __restrict__ oW, const float* __restrict__ ob,
                                 float* __restrict__ out) {
    int g = blockIdx.x;
    int t = threadIdx.x;
    __shared__ int bounds[2];
    __shared__ float partial[7][H];
    __shared__ float pooled[H];
    if (t == 0) {
        int lo = 0, hi = N;
        while (lo < hi) { int mid = (lo + hi) >> 1; if (batch[mid] < g) lo = mid + 1; else hi = mid; }
        bounds[0] = lo;
        int lo2 = lo, hi2 = N;
        while (lo2 < hi2) { int mid = (lo2 + hi2) >> 1; if (batch[mid] < g + 1) lo2 = mid + 1; else hi2 = mid; }
        bounds[1] = lo2;
    }
    __syncthreads();
    int rlo = bounds[0], rhi = bounds[1];
    int cntg = rhi - rlo;
    int gg = t / H;
    int j = t - gg * H;
    if (gg < 7) {
        float acc = 0.f;
        for (int r = rlo + gg; r < rhi; r += 7) acc += h[(long)r * HP + j];
        partial[gg][j] = acc;
    }
    __syncthreads();
    if (t < H) {
        float s = 0.f;
#pragma unroll
        for (int k = 0; k < 7; ++k) s += partial[k][t];
        pooled[t] = s / fmaxf((float)cntg, 1.f);
    }
    __syncthreads();
    if (t < HOUT) {
        float acc = pb[t];
#pragma unroll
        for (int k = 0; k < H; ++k) acc += pooled[k] * pW[k * HOUT + t];
        float z = fmaxf(acc, 0.f) + log1pf(expf(-fabsf(acc)));  // softplus
        float pr = z * oW[t];
#pragma unroll
        for (int off = 32; off; off >>= 1) pr += __shfl_down(pr, off);
        if (t == 0) out[g] = pr + ob[0];
    }
}

static inline int grid_for(long n, int block = 256, long cap = 2048) {
    long b = (n + block - 1) / block;
    if (b > cap) b = cap;
    if (b < 1) b = 1;
    return (int)b;
}

extern "C" void kernel_launch(void* const* d_in, const int* in_sizes, int n_in,
                              void* d_out, int out_size, void* d_ws, size_t ws_size,
                              hipStream_t stream) {
    const float* x       = (const float*)d_in[0];
    const float* he      = (const float*)d_in[1];
    const int*   ni      = (const int*)d_in[2];
    const int*   ei      = (const int*)d_in[3];
    const int*   batch   = (const int*)d_in[4];
    const float* embed_W = (const float*)d_in[5];
    const float* embed_b = (const float*)d_in[6];
    const float* lin_W   = (const float*)d_in[7];   // [L,H,H]
    const float* att     = (const float*)d_in[8];   // [L,2H]
    const float* conv_b  = (const float*)d_in[9];   // [L,H]
    const float* proj_W  = (const float*)d_in[10];  // [H,HOUT]
    const float* proj_b  = (const float*)d_in[11];
    const float* out_W   = (const float*)d_in[12];  // [HOUT,1]
    const float* out_b   = (const float*)d_in[13];
    float* out = (float*)d_out;

    const int N    = in_sizes[0] / F_IN;  // 100000
    const int E    = in_sizes[1] / H;     // 50000
    const int NINC = in_sizes[2];         // 2000000
    const int G    = out_size;            // 256

    char* w = (char*)d_ws;
    auto alloc = [&](size_t bytes) {
        char* p = w;
        w += (bytes + 255) & ~(size_t)255;
        return p;
    };
    float*  h       = (float*)alloc((size_t)N * HP * 4);
    __half* xl_h    = (__half*)alloc((size_t)N * HP2 * 2);
    __half* e_out_h = (__half*)alloc((size_t)E * HP2 * 2);
    float*  s_n     = (float*)alloc((size_t)N * 4);
    float*  epack   = (float*)alloc((size_t)E * 16);   // float4 {s_e, m, rec, -}
    float*  w1      = (float*)alloc((size_t)NL * H * 4);
    float*  w2      = (float*)alloc((size_t)NL * H * 4);
    int*    ecnt    = (int*)alloc((size_t)E * 4);
    int*    eptr    = (int*)alloc((size_t)(E + 1) * 4);
    int*    ecur    = (int*)alloc((size_t)E * 4);
    int*    ncnt    = (int*)alloc((size_t)N * 4);
    int*    nptr    = (int*)alloc((size_t)(N + 1) * 4);
    int*    ncur    = (int*)alloc((size_t)N * 4);
    int*    enode   = (int*)alloc((size_t)NINC * 4);
    int*    nedge   = (int*)alloc((size_t)NINC * 4);
    int*    bsums   = (int*)alloc((size_t)256 * 4);

    const int BLK = 256;
    int gE   = grid_for(E);
    int wN   = (N + NSLICE - 1) / NSLICE;
    int wE   = (E + NSLICE - 1) / NSLICE;
    int nbE  = (E + SCH - 1) / SCH;
    int nbN  = (N + SCH - 1) / SCH;

    // ---- CSR build ----
    (void)hipMemsetAsync(ncnt, 0, (size_t)N * 4, stream);
    (void)hipMemsetAsync(ecnt, 0, (size_t)E * 4, stream);
    count_sliced_kernel<<<2048, BLK, 0, stream>>>(ni, ei, ncnt, ecnt, NINC, wN, wE);
    bsum2_kernel<<<nbE + nbN, 256, 0, stream>>>(ecnt, nbE, E, ncnt, N, bsums);
    scan_bsums_kernel<<<1, 64, 0, stream>>>(bsums, nbE, nbN);
    scan_write2_kernel<<<nbE + nbN, 256, 0, stream>>>(ecnt, eptr, ecur, nbE, E,
                                                      ncnt, nptr, ncur, N, bsums, NINC);
    csr_fill_sliced_kernel<<<2048, BLK, 0, stream>>>(ni, ei, ecur, ncur, enode, nedge,
                                                     NINC, wN, wE);

    // ---- folded att vectors + fused embed (h, xl_h, s_n for layer 0) ----
    wfold_all_kernel<<<1, 64, 0, stream>>>(lin_W, att, w1, w2);
    int gRow = (N + 3) / 4;   // 1 wave per row
    embed_fused_kernel<<<gRow, BLK, 0, stream>>>(x, embed_W, embed_b, lin_W, w1,
                                                 h, xl_h, s_n, N);

    // ---- layers ----
    int gEdge = (E + 3) / 4;   // 1 wave per edge
    int gNode = (N + 3) / 4;   // 1 wave per node
    for (int l = 0; l < NL; ++l) {
        const float* b = conv_b + (size_t)l * H;
        int lnext = (l + 1 < NL) ? l + 1 : l;   // valid pointers for l=2 (unused)
        const float* Wn  = lin_W + (size_t)lnext * H * H;
        const float* w1n = w1 + (size_t)lnext * H;
        int produce = (l + 1 < NL) ? 1 : 0;

        rowdot_he_kernel<<<gE, BLK, 0, stream>>>(he, w2 + (size_t)l * H, epack, E, 4);
        edge_pass_kernel<<<gEdge, BLK, 0, stream>>>(eptr, enode, s_n, epack, xl_h, e_out_h, E);
        node_pass_kernel<<<gNode, BLK, 0, stream>>>(nptr, nedge, s_n, epack, e_out_h, b,
                                                    Wn, w1n, produce, h, xl_h, s_n, N);
    }

    // ---- pooling + head ----
    pool_head_kernel<<<G, BLK, 0, stream>>>(h, batch, N, proj_W, proj_b, out_W, out_b, out);
}

// Round 16
// 1065.786 us; speedup vs baseline: 1.0873x; 1.0873x over previous
//
#include <hip/hip_runtime.h>
#include <hip/hip_bf16.h>
#include <hip/hip_fp16.h>
#include <limits.h>
#include <math.h>

#define F_IN 92
#define H 35
#define HP 36        // fp32 row stride (h): 144 B = 9 x float4
#define HP2 36       // fp16 row stride (xl, e_out): 72 B = 9 x 8B
#define HOUT 64
#define NL 3
#define NEG_SLOPE 0.2f
#define NSLICE 8
#define SCH 2048     // scan chunk per block (256 thr x 8)

typedef int iv4 __attribute__((ext_vector_type(4)));

// ------------------------------------------------------------------
// dense kernels (thread-per-element — validated r13/r14 structure)
// ------------------------------------------------------------------

// h[n,j] = sum_k x[n,k] * W[k,j] + b[j]   (W: F_IN x H), h stride HP (fp32)
__global__ void embed_kernel(const float* __restrict__ x, const float* __restrict__ W,
                             const float* __restrict__ b, float* __restrict__ h, int N) {
    __shared__ float sW[F_IN * H];
    for (int t = threadIdx.x; t < F_IN * H; t += blockDim.x) sW[t] = W[t];
    __syncthreads();
    int total = N * HP;
    int stride = gridDim.x * blockDim.x;
    for (int t = blockIdx.x * blockDim.x + threadIdx.x; t < total; t += stride) {
        int n = t / HP, j = t - n * HP;
        if (j < H) {
            const float* xr = x + (long)n * F_IN;
            float acc = b[j];
#pragma unroll 4
            for (int k = 0; k < F_IN; ++k) acc += xr[k] * sW[k * H + j];
            h[t] = acc;
        } else {
            h[t] = 0.f;
        }
    }
}

// xl_h[r,j] = (half) sum_k h[r,k] * W[k,j]   (in fp32 stride HP, out fp16 stride HP2)
__global__ void lin_h_kernel(const float* __restrict__ in, const float* __restrict__ W,
                             __half* __restrict__ out, int R) {
    __shared__ float sW[H * H];
    for (int t = threadIdx.x; t < H * H; t += blockDim.x) sW[t] = W[t];
    __syncthreads();
    int total = R * HP2;
    int stride = gridDim.x * blockDim.x;
    for (int t = blockIdx.x * blockDim.x + threadIdx.x; t < total; t += stride) {
        int r = t / HP2, j = t - r * HP2;
        if (j < H) {
            const float* ir = in + (long)r * HP;
            float acc = 0.f;
#pragma unroll
            for (int k = 0; k < H; ++k) acc += ir[k] * sW[k * H + j];
            out[t] = __float2half(acc);
        } else {
            out[t] = __float2half(0.f);
        }
    }
}

// s[r] = dot(in[r,:], vec[0:H])  -> s[r*stride_out]; in fp32 stride HP
__global__ void rowdot_kernel(const float* __restrict__ in, const float* __restrict__ vec,
                              float* __restrict__ s, int R, int stride_out) {
    __shared__ float sA[H];
    for (int t = threadIdx.x; t < H; t += blockDim.x) sA[t] = vec[t];
    __syncthreads();
    int stride = gridDim.x * blockDim.x;
    for (int r = blockIdx.x * blockDim.x + threadIdx.x; r < R; r += stride) {
        const float* xr = in + (long)r * HP;
        float acc = 0.f;
#pragma unroll
        for (int k = 0; k < H; ++k) acc += xr[k] * sA[k];
        s[(long)r * stride_out] = acc;
    }
}

// he_s[r] = dot(he[r,:], vec)  (he is UNPADDED stride H from input)
__global__ void rowdot_he_kernel(const float* __restrict__ in, const float* __restrict__ vec,
                                 float* __restrict__ s, int R, int stride_out) {
    __shared__ float sA[H];
    for (int t = threadIdx.x; t < H; t += blockDim.x) sA[t] = vec[t];
    __syncthreads();
    int stride = gridDim.x * blockDim.x;
    for (int r = blockIdx.x * blockDim.x + threadIdx.x; r < R; r += stride) {
        const float* xr = in + (long)r * H;
        float acc = 0.f;
#pragma unroll
        for (int k = 0; k < H; ++k) acc += xr[k] * sA[k];
        s[(long)r * stride_out] = acc;
    }
}

// w1[l*H+k] = sum_j W_l[k,j]*a_n[j];  w2[l*H+k] = sum_j W_l[k,j]*a_e[j]
__global__ void wfold_all_kernel(const float* __restrict__ lin_W, const float* __restrict__ att,
                                 float* __restrict__ w1, float* __restrict__ w2) {
    int k = threadIdx.x;
    if (k < H) {
        for (int l = 0; l < NL; ++l) {
            const float* W  = lin_W + (size_t)l * H * H;
            const float* an = att + (size_t)l * 2 * H;
            const float* ae = an + H;
            float a1 = 0.f, a2 = 0.f;
#pragma unroll
            for (int j = 0; j < H; ++j) {
                float wkj = W[k * H + j];
                a1 += wkj * an[j];
                a2 += wkj * ae[j];
            }
            w1[l * H + k] = a1;
            w2[l * H + k] = a2;
        }
    }
}

// ------------------------------------------------------------------
// CSR build — sliced scatter (r8) + hierarchical scan (r9), validated
// ------------------------------------------------------------------

__global__ void count_sliced_kernel(const int* __restrict__ ni, const int* __restrict__ ei,
                                    int* __restrict__ ncnt, int* __restrict__ ecnt,
                                    int ninc, int wN, int wE) {
    int s = blockIdx.x & (NSLICE - 1);
    int loN = s * wN, hiN = loN + wN;
    int loE = s * wE, hiE = loE + wE;
    int nblk = gridDim.x >> 3;
    int bid = blockIdx.x >> 3;
    int nvec = ninc >> 2;
    int stride = nblk * blockDim.x;
    for (int q = bid * blockDim.x + threadIdx.x; q < nvec; q += stride) {
        iv4 v4 = __builtin_nontemporal_load((const iv4*)ni + q);
        iv4 e4 = __builtin_nontemporal_load((const iv4*)ei + q);
#pragma unroll
        for (int u = 0; u < 4; ++u) {
            int e = e4[u], v = v4[u];
            if (e >= loE && e < hiE) atomicAdd(&ecnt[e], 1);
            if (v >= loN && v < hiN) atomicAdd(&ncnt[v], 1);
        }
    }
    if (bid == 0) {
        for (int i = (nvec << 2) + threadIdx.x; i < ninc; i += blockDim.x) {
            int v = ni[i], e = ei[i];
            if (e >= loE && e < hiE) atomicAdd(&ecnt[e], 1);
            if (v >= loN && v < hiN) atomicAdd(&ncnt[v], 1);
        }
    }
}

__device__ __forceinline__ int wave_sum_i(int s) {
#pragma unroll
    for (int off = 32; off; off >>= 1) s += __shfl_xor(s, off);
    return s;
}

__global__ void bsum2_kernel(const int* __restrict__ cnt0, int nb0, int n0,
                             const int* __restrict__ cnt1, int n1,
                             int* __restrict__ bsums) {
    int b = blockIdx.x;
    const int* c; int n; int base;
    if (b < nb0) { c = cnt0; n = n0; base = b * SCH; }
    else         { c = cnt1; n = n1; base = (b - nb0) * SCH; }
    int t = threadIdx.x;
    int hi = base + SCH; if (hi > n) hi = n;
    int s = 0;
    for (int i = base + t; i < hi; i += 256) s += c[i];
    s = wave_sum_i(s);
    __shared__ int ws[4];
    if ((t & 63) == 0) ws[t >> 6] = s;
    __syncthreads();
    if (t == 0) bsums[b] = ws[0] + ws[1] + ws[2] + ws[3];
}

__global__ void scan_bsums_kernel(int* __restrict__ bsums, int nb0, int nb1) {
    int t = threadIdx.x;
    if (t == 0) {
        int acc = 0;
        for (int i = 0; i < nb0; ++i) { int v = bsums[i]; bsums[i] = acc; acc += v; }
    } else if (t == 1) {
        int acc = 0;
        for (int i = nb0; i < nb0 + nb1; ++i) { int v = bsums[i]; bsums[i] = acc; acc += v; }
    }
}

__global__ void scan_write2_kernel(const int* __restrict__ cnt0, int* __restrict__ ptr0,
                                   int* __restrict__ cur0, int nb0, int n0,
                                   const int* __restrict__ cnt1, int* __restrict__ ptr1,
                                   int* __restrict__ cur1, int n1,
                                   const int* __restrict__ bsums, int ninc) {
    int b = blockIdx.x;
    const int* c; int* p; int* u; int n; int base;
    if (b < nb0) { c = cnt0; p = ptr0; u = cur0; n = n0; base = b * SCH; }
    else         { c = cnt1; p = ptr1; u = cur1; n = n1; base = (b - nb0) * SCH; }
    int off = bsums[b];
    int t = threadIdx.x;
    int lo = base + t * 8;
    int vals[8];
    int s = 0;
#pragma unroll
    for (int k = 0; k < 8; ++k) {
        int i = lo + k;
        int v = (i < n) ? c[i] : 0;
        vals[k] = s;
        s += v;
    }
    __shared__ int lds[256];
    lds[t] = s;
    __syncthreads();
    for (int o2 = 1; o2 < 256; o2 <<= 1) {
        int v = (t >= o2) ? lds[t - o2] : 0;
        __syncthreads();
        lds[t] += v;
        __syncthreads();
    }
    int tbase = off + ((t == 0) ? 0 : lds[t - 1]);
#pragma unroll
    for (int k = 0; k < 8; ++k) {
        int i = lo + k;
        if (i < n) { int val = tbase + vals[k]; p[i] = val; u[i] = val; }
    }
    if (b == 0 && t == 0) { ptr0[n0] = ninc; ptr1[n1] = ninc; }
}

__global__ void csr_fill_sliced_kernel(const int* __restrict__ ni, const int* __restrict__ ei,
                                       int* __restrict__ ecur, int* __restrict__ ncur,
                                       int* __restrict__ enode, int* __restrict__ nedge,
                                       int ninc, int wN, int wE) {
    int s = blockIdx.x & (NSLICE - 1);
    int loN = s * wN, hiN = loN + wN;
    int loE = s * wE, hiE = loE + wE;
    int nblk = gridDim.x >> 3;
    int bid = blockIdx.x >> 3;
    int nvec = ninc >> 2;
    int stride = nblk * blockDim.x;
    for (int q = bid * blockDim.x + threadIdx.x; q < nvec; q += stride) {
        iv4 v4 = __builtin_nontemporal_load((const iv4*)ni + q);
        iv4 e4 = __builtin_nontemporal_load((const iv4*)ei + q);
#pragma unroll
        for (int u = 0; u < 4; ++u) {
            int e = e4[u], v = v4[u];
            if (e >= loE && e < hiE) {
                int p = atomicAdd(&ecur[e], 1);
                enode[p] = v;
            }
            if (v >= loN && v < hiN) {
                int p = atomicAdd(&ncur[v], 1);
                nedge[p] = e;
            }
        }
    }
    if (bid == 0) {
        for (int i = (nvec << 2) + threadIdx.x; i < ninc; i += blockDim.x) {
            int v = ni[i], e = ei[i];
            if (e >= loE && e < hiE) { int p = atomicAdd(&ecur[e], 1); enode[p] = v; }
            if (v >= loN && v < hiN) { int p = atomicAdd(&ncur[v], 1); nedge[p] = e; }
        }
    }
}

// ------------------------------------------------------------------
// fused sparse passes — 7 groups x 9 lanes; fp16 rows, fp32 accumulation
// ------------------------------------------------------------------

__device__ __forceinline__ float wave_max(float m) {
#pragma unroll
    for (int off = 32; off; off >>= 1) m = fmaxf(m, __shfl_xor(m, off));
    return m;
}
__device__ __forceinline__ float wave_sum(float s) {
#pragma unroll
    for (int off = 32; off; off >>= 1) s += __shfl_xor(s, off);
    return s;
}

__device__ __forceinline__ void grouped_gather_h(const __half* __restrict__ src,
                                                 const float* shA, const int* shV,
                                                 int cnt, int g, int l, float4& acc) {
    if (g < 7) {
        for (int k = g; k < cnt; k += 7) {
            float ak = shA[k];
            int vk = shV[k];
            uint2 raw = ((const uint2*)(src + (size_t)vk * HP2))[l];
            __half2 h01 = *reinterpret_cast<const __half2*>(&raw.x);
            __half2 h23 = *reinterpret_cast<const __half2*>(&raw.y);
            float2 f01 = __half22float2(h01);
            float2 f23 = __half22float2(h23);
            acc.x += ak * f01.x; acc.y += ak * f01.y;
            acc.z += ak * f23.x; acc.w += ak * f23.y;
        }
    }
}

__device__ __forceinline__ void group_reduce(float4& acc, int lane, int l) {
#pragma unroll
    for (int gg = 1; gg < 7; ++gg) {
        int src = l + 9 * gg;
        float ox = __shfl(acc.x, src);
        float oy = __shfl(acc.y, src);
        float oz = __shfl(acc.z, src);
        float ow = __shfl(acc.w, src);
        if (lane < 9) { acc.x += ox; acc.y += oy; acc.z += oz; acc.w += ow; }
    }
}

// per edge e: softmax + weighted accumulation into e_out_h[e,:] (fp16, stride HP2)
__global__ void edge_pass_kernel(const int* __restrict__ eptr, const int* __restrict__ enode,
                                 const float* __restrict__ s_n, float* __restrict__ epack,
                                 const __half* __restrict__ xl_h,
                                 __half* __restrict__ e_out_h, int E) {
    __shared__ float shA[4][64];
    __shared__ int   shV[4][64];
    int lane = threadIdx.x & 63;
    int ws = threadIdx.x >> 6;
    int g = lane / 9, l = lane - g * 9;
    int wid = (blockIdx.x * blockDim.x + threadIdx.x) >> 6;
    int nw = (gridDim.x * blockDim.x) >> 6;
    for (int e = wid; e < E; e += nw) {
        int lo = eptr[e], hi = eptr[e + 1];
        int deg = hi - lo;
        float se = epack[4 * (long)e];
        float binv = deg > 0 ? 1.f / (float)deg : 0.f;
        float4 acc = {0.f, 0.f, 0.f, 0.f};
        float mm, rec;
        if (deg <= 64) {
            int v = 0; float sc = -INFINITY;
            if (lane < deg) {
                v = enode[lo + lane];
                sc = s_n[v] + se;
                sc = sc >= 0.f ? sc : NEG_SLOPE * sc;
            }
            float m = wave_max(sc);
            mm = (m == -INFINITY) ? 0.f : m;
            float ex = (lane < deg) ? expf(sc - mm) : 0.f;
            float s = wave_sum(ex);
            rec = 1.f / (s + 1e-16f);
            shA[ws][lane] = ex * rec * binv;
            shV[ws][lane] = v;
            grouped_gather_h(xl_h, shA[ws], shV[ws], deg, g, l, acc);
        } else {
            float m = -INFINITY;
            for (int k = lo + lane; k < hi; k += 64) {
                float sc = s_n[enode[k]] + se;
                sc = sc >= 0.f ? sc : NEG_SLOPE * sc;
                m = fmaxf(m, sc);
            }
            m = wave_max(m);
            mm = (m == -INFINITY) ? 0.f : m;
            float s = 0.f;
            for (int k = lo + lane; k < hi; k += 64) {
                float sc = s_n[enode[k]] + se;
                sc = sc >= 0.f ? sc : NEG_SLOPE * sc;
                s += expf(sc - mm);
            }
            s = wave_sum(s);
            rec = 1.f / (s + 1e-16f);
            float cb = rec * binv;
            for (int base = lo; base < hi; base += 64) {
                int v = 0; float a = 0.f;
                if (base + lane < hi) {
                    v = enode[base + lane];
                    float sc = s_n[v] + se;
                    sc = sc >= 0.f ? sc : NEG_SLOPE * sc;
                    a = expf(sc - mm) * cb;
                }
                shA[ws][lane] = a;
                shV[ws][lane] = v;
                int cn = hi - base; if (cn > 64) cn = 64;
                grouped_gather_h(xl_h, shA[ws], shV[ws], cn, g, l, acc);
            }
        }
        group_reduce(acc, lane, l);
        if (lane < 9) {
            __half2 p0 = __floats2half2_rn(acc.x, acc.y);
            __half2 p1 = __floats2half2_rn(acc.z, acc.w);
            uint2 wv;
            wv.x = *reinterpret_cast<unsigned*>(&p0);
            wv.y = *reinterpret_cast<unsigned*>(&p1);
            ((uint2*)(e_out_h + (size_t)e * HP2))[lane] = wv;
        }
        if (lane == 0) { epack[4 * (long)e + 1] = mm; epack[4 * (long)e + 2] = rec; }
    }
}

// per node v: h[v,:] = Dinv * sum alpha_i * e_out_h[e_i,:] + bias  (h fp32)
// fused epilogue (produce=1): xl_h[v,:] = h[v,:] @ Wn  (fp16), s_n[v] = h[v,:] @ w1n
__global__ void node_pass_kernel(const int* __restrict__ nptr, const int* __restrict__ nedge,
                                 const float* __restrict__ s_n_in, const float* __restrict__ epack,
                                 const __half* __restrict__ e_out_h, const float* __restrict__ bias,
                                 const float* __restrict__ Wn, const float* __restrict__ w1n,
                                 int produce,
                                 float* __restrict__ hout, __half* __restrict__ xl_out,
                                 float* __restrict__ snout, int N) {
    __shared__ float shA[4][64];
    __shared__ int   shE[4][64];
    __shared__ float sb[HP];
    __shared__ float sW[H * H];
    __shared__ float sw1[H];
    __shared__ float shrow[4][HP];
    __shared__ __half shh[4][HP];
    if (threadIdx.x < HP) sb[threadIdx.x] = (threadIdx.x < H) ? bias[threadIdx.x] : 0.f;
    if (produce) {
        for (int t = threadIdx.x; t < H * H; t += blockDim.x) sW[t] = Wn[t];
        if (threadIdx.x < H) sw1[threadIdx.x] = w1n[threadIdx.x];
    }
    __syncthreads();
    int lane = threadIdx.x & 63;
    int ws = threadIdx.x >> 6;
    int g = lane / 9, l = lane - g * 9;
    int wid = (blockIdx.x * blockDim.x + threadIdx.x) >> 6;
    int nw = (gridDim.x * blockDim.x) >> 6;
    for (int v = wid; v < N; v += nw) {
        int lo = nptr[v], hi = nptr[v + 1];
        int deg = hi - lo;
        float dinv = deg > 0 ? 1.f / (float)deg : 0.f;
        float sn = s_n_in[v];
        float4 acc = {0.f, 0.f, 0.f, 0.f};
        if (deg <= 64) {
            int e = 0; float a = 0.f;
            if (lane < deg) {
                e = nedge[lo + lane];
                float4 p = ((const float4*)epack)[e];
                float sc = sn + p.x;
                sc = sc >= 0.f ? sc : NEG_SLOPE * sc;
                a = expf(sc - p.y) * p.z;
            }
            shA[ws][lane] = a;
            shE[ws][lane] = e;
            grouped_gather_h(e_out_h, shA[ws], shE[ws], deg, g, l, acc);
        } else {
            for (int base = lo; base < hi; base += 64) {
                int e = 0; float a = 0.f;
                if (base + lane < hi) {
                    e = nedge[base + lane];
                    float4 p = ((const float4*)epack)[e];
                    float sc = sn + p.x;
                    sc = sc >= 0.f ? sc : NEG_SLOPE * sc;
                    a = expf(sc - p.y) * p.z;
                }
                shA[ws][lane] = a;
                shE[ws][lane] = e;
                int cn = hi - base; if (cn > 64) cn = 64;
                grouped_gather_h(e_out_h, shA[ws], shE[ws], cn, g, l, acc);
            }
        }
        group_reduce(acc, lane, l);
        if (lane < 9) {
            float4 bb = ((const float4*)sb)[lane];
            float4 r;
            r.x = dinv * acc.x + bb.x;
            r.y = dinv * acc.y + bb.y;
            r.z = dinv * acc.z + bb.z;
            r.w = dinv * acc.w + bb.w;
            ((float4*)(hout + (size_t)v * HP))[lane] = r;
            if (produce) ((float4*)&shrow[ws][0])[lane] = r;   // stage row (pad col = 0)
        }
        if (produce) {
            // wave-local LDS dep: lanes read the row lanes 0..8 just wrote
            if (lane < H) {
                float a = 0.f;
#pragma unroll
                for (int k = 0; k < H; ++k) a += shrow[ws][k] * sW[k * H + lane];
                shh[ws][lane] = __float2half(a);
            } else if (lane == H) {
                float a2 = 0.f;
#pragma unroll
                for (int k = 0; k < H; ++k) a2 += shrow[ws][k] * sw1[k];
                snout[v] = a2;
                shh[ws][H] = __float2half(0.f);
            }
            if (lane < 9) ((uint2*)(xl_out + (size_t)v * HP2))[lane] = ((const uint2*)&shh[ws][0])[lane];
        }
    }
}

// ------------------------------------------------------------------
// fused pooling (batch sorted -> binary search) + MLP head (h stride HP)
// ------------------------------------------------------------------
__global__ void pool_head_kernel(const float* __restrict__ h, const int* __restrict__ batch,
                                 int N, const float* __restrict__ pW, const float* __restrict__ pb,
                                 const float* __restrict__ oW, const float* __restrict__ ob,
                                 float* __restrict__ out) {
    int g = blockIdx.x;
    int t = threadIdx.x;
    __shared__ int bounds[2];
    __shared__ float partial[7][H];
    __shared__ float pooled[H];
    if (t == 0) {
        int lo = 0, hi = N;
        while (lo < hi) { int mid = (lo + hi) >> 1; if (batch[mid] < g) lo = mid + 1; else hi = mid; }
        bounds[0] = lo;
        int lo2 = lo, hi2 = N;
        while (lo2 < hi2) { int mid = (lo2 + hi2) >> 1; if (batch[mid] < g + 1) lo2 = mid + 1; else hi2 = mid; }
        bounds[1] = lo2;
    }
    __syncthreads();
    int rlo = bounds[0], rhi = bounds[1];
    int cntg = rhi - rlo;
    int gg = t / H;
    int j = t - gg * H;
    if (gg < 7) {
        float acc = 0.f;
        for (int r = rlo + gg; r < rhi; r += 7) acc += h[(long)r * HP + j];
        partial[gg][j] = acc;
    }
    __syncthreads();
    if (t < H) {
        float s = 0.f;
#pragma unroll
        for (int k = 0; k < 7; ++k) s += partial[k][t];
        pooled[t] = s / fmaxf((float)cntg, 1.f);
    }
    __syncthreads();
    if (t < HOUT) {
        float acc = pb[t];
#pragma unroll
        for (int k = 0; k < H; ++k) acc += pooled[k] * pW[k * HOUT + t];
        float z = fmaxf(acc, 0.f) + log1pf(expf(-fabsf(acc)));  // softplus
        float pr = z * oW[t];
#pragma unroll
        for (int off = 32; off; off >>= 1) pr += __shfl_down(pr, off);
        if (t == 0) out[g] = pr + ob[0];
    }
}

static inline int grid_for(long n, int block = 256, long cap = 2048) {
    long b = (n + block - 1) / block;
    if (b > cap) b = cap;
    if (b < 1) b = 1;
    return (int)b;
}

extern "C" void kernel_launch(void* const* d_in, const int* in_sizes, int n_in,
                              void* d_out, int out_size, void* d_ws, size_t ws_size,
                              hipStream_t stream) {
    const float* x       = (const float*)d_in[0];
    const float* he      = (const float*)d_in[1];
    const int*   ni      = (const int*)d_in[2];
    const int*   ei      = (const int*)d_in[3];
    const int*   batch   = (const int*)d_in[4];
    const float* embed_W = (const float*)d_in[5];
    const float* embed_b = (const float*)d_in[6];
    const float* lin_W   = (const float*)d_in[7];   // [L,H,H]
    const float* att     = (const float*)d_in[8];   // [L,2H]
    const float* conv_b  = (const float*)d_in[9];   // [L,H]
    const float* proj_W  = (const float*)d_in[10];  // [H,HOUT]
    const float* proj_b  = (const float*)d_in[11];
    const float* out_W   = (const float*)d_in[12];  // [HOUT,1]
    const float* out_b   = (const float*)d_in[13];
    float* out = (float*)d_out;

    const int N    = in_sizes[0] / F_IN;  // 100000
    const int E    = in_sizes[1] / H;     // 50000
    const int NINC = in_sizes[2];         // 2000000
    const int G    = out_size;            // 256

    char* w = (char*)d_ws;
    auto alloc = [&](size_t bytes) {
        char* p = w;
        w += (bytes + 255) & ~(size_t)255;
        return p;
    };
    float*  h       = (float*)alloc((size_t)N * HP * 4);
    __half* xl_h    = (__half*)alloc((size_t)N * HP2 * 2);
    __half* e_out_h = (__half*)alloc((size_t)E * HP2 * 2);
    float*  s_n     = (float*)alloc((size_t)N * 4);
    float*  epack   = (float*)alloc((size_t)E * 16);   // float4 {s_e, m, rec, -}
    float*  w1      = (float*)alloc((size_t)NL * H * 4);
    float*  w2      = (float*)alloc((size_t)NL * H * 4);
    int*    ecnt    = (int*)alloc((size_t)E * 4);
    int*    eptr    = (int*)alloc((size_t)(E + 1) * 4);
    int*    ecur    = (int*)alloc((size_t)E * 4);
    int*    ncnt    = (int*)alloc((size_t)N * 4);
    int*    nptr    = (int*)alloc((size_t)(N + 1) * 4);
    int*    ncur    = (int*)alloc((size_t)N * 4);
    int*    enode   = (int*)alloc((size_t)NINC * 4);
    int*    nedge   = (int*)alloc((size_t)NINC * 4);
    int*    bsums   = (int*)alloc((size_t)256 * 4);

    const int BLK = 256;
    int gNH  = grid_for((long)N * HP);
    int gN   = grid_for(N);
    int gE   = grid_for(E);
    int wN   = (N + NSLICE - 1) / NSLICE;
    int wE   = (E + NSLICE - 1) / NSLICE;
    int nbE  = (E + SCH - 1) / SCH;
    int nbN  = (N + SCH - 1) / SCH;

    // ---- CSR build ----
    (void)hipMemsetAsync(ncnt, 0, (size_t)N * 4, stream);
    (void)hipMemsetAsync(ecnt, 0, (size_t)E * 4, stream);
    count_sliced_kernel<<<2048, BLK, 0, stream>>>(ni, ei, ncnt, ecnt, NINC, wN, wE);
    bsum2_kernel<<<nbE + nbN, 256, 0, stream>>>(ecnt, nbE, E, ncnt, N, bsums);
    scan_bsums_kernel<<<1, 64, 0, stream>>>(bsums, nbE, nbN);
    scan_write2_kernel<<<nbE + nbN, 256, 0, stream>>>(ecnt, eptr, ecur, nbE, E,
                                                      ncnt, nptr, ncur, N, bsums, NINC);
    csr_fill_sliced_kernel<<<2048, BLK, 0, stream>>>(ni, ei, ecur, ncur, enode, nedge,
                                                     NINC, wN, wE);

    // ---- embed (thread-per-element, r14-validated) + layer-0 xl/s_n ----
    wfold_all_kernel<<<1, 64, 0, stream>>>(lin_W, att, w1, w2);
    embed_kernel<<<gNH, BLK, 0, stream>>>(x, embed_W, embed_b, h, N);
    lin_h_kernel<<<gNH, BLK, 0, stream>>>(h, lin_W, xl_h, N);
    rowdot_kernel<<<gN, BLK, 0, stream>>>(h, w1, s_n, N, 1);

    // ---- layers (node_pass fused epilogue produces next layer's xl/s_n) ----
    int gEdge = (E + 3) / 4;   // 1 wave per edge
    int gNode = (N + 3) / 4;   // 1 wave per node
    for (int l = 0; l < NL; ++l) {
        const float* b = conv_b + (size_t)l * H;
        int lnext = (l + 1 < NL) ? l + 1 : l;   // valid pointers for l=2 (unused)
        const float* Wn  = lin_W + (size_t)lnext * H * H;
        const float* w1n = w1 + (size_t)lnext * H;
        int produce = (l + 1 < NL) ? 1 : 0;

        rowdot_he_kernel<<<gE, BLK, 0, stream>>>(he, w2 + (size_t)l * H, epack, E, 4);
        edge_pass_kernel<<<gEdge, BLK, 0, stream>>>(eptr, enode, s_n, epack, xl_h, e_out_h, E);
        node_pass_kernel<<<gNode, BLK, 0, stream>>>(nptr, nedge, s_n, epack, e_out_h, b,
                                                    Wn, w1n, produce, h, xl_h, s_n, N);
    }

    // ---- pooling + head ----
    pool_head_kernel<<<G, BLK, 0, stream>>>(h, batch, N, proj_W, proj_b, out_W, out_b, out);
}